// Round 22
// baseline (218.706 us; speedup 1.0000x reference)
//
#include <hip/hip_runtime.h>
#include <math.h>

#define BB 4
#define NN 8192
#define MM 2048
#define CC 64
#define KNB 32
#define CIN 67   // 3 + CC
#define H1 64
#define H2 128
#define XP 36    // padded row stride for x^T / h1^T tile (float4-aligned)
#define AB 4     // anchors per mlp block
#define KT 512   // knn block threads
#define PJ 16    // points per knn thread (NN / KT)
#define KAB 4    // anchors per knn block

// ---------------- init: zero per-batch maxnorm cells ----------------
__global__ void init_kernel(int* maxnorm) {
    if (threadIdx.x < BB) maxnorm[threadIdx.x] = 0;
}

// ---------------- coord4 pack: (cx,cy,cz,c2) per point; c2 formula bit-identical ----------------
__global__ __launch_bounds__(256) void coord4_kernel(const float* __restrict__ coord,
                                                     float4* __restrict__ c4) {
    const int t = blockIdx.x * 256 + threadIdx.x;   // t in [0, BB*NN)
    if (t < BB * NN) {
        float cx = coord[t * 3 + 0], cy = coord[t * 3 + 1], cz = coord[t * 3 + 2];
        float c2 = __fadd_rn(__fadd_rn(__fmul_rn(cx, cx), __fmul_rn(cy, cy)), __fmul_rn(cz, cz));
        float4 q; q.x = cx; q.y = cy; q.z = cz; q.w = c2;
        c4[t] = q;
    }
}

// ---------------- kNN: 512 threads, 16 pts/thread, FOUR anchors per block ----------------
// Per-anchor selection math byte-identical to validated r20/r21 (monotone keys,
// radix rank, <T emission, lowest-index ties; set-level => partition-independent).
// 4x amortization of loads/addressing/barriers. bound (512,4): VGPR budget 128
// (r21's (512,8) forced 32+spills). Select phase: threads<256 -> anchors 0,1;
// threads>=256 -> anchors 2,3 (validated dual-anchor scan, run twice in parallel).
__global__ __launch_bounds__(KT, 4) void knn_kernel(
    const float4* __restrict__ c4buf, const float* __restrict__ anchor_coord,
    int* __restrict__ idxbuf, int* __restrict__ maxnorm)
{
    __shared__ unsigned hist[KAB][2][256];  // [anchor][copy][bin]; waves 0-3 copy 0, 4-7 copy 1
    __shared__ unsigned wmax[KAB][8];
    __shared__ unsigned wtot[KAB][4];
    __shared__ unsigned bc[KAB][2];         // [anchor][0]=bin, [anchor][1]=rank
    __shared__ unsigned nsel[KAB];
    __shared__ int      selcell[KAB];
    __shared__ int      sel_s[KAB][KNB];

    const int a0 = blockIdx.x * KAB;        // MM%KAB==0: all 4 anchors in same batch
    const int b  = a0 >> 11;                // / MM
    const int mi = a0 & (MM - 1);
    const int tid = threadIdx.x;
    const int w = tid >> 6, lane = tid & 63;

    const float axA = anchor_coord[(b * MM + mi) * 3 + 0];
    const float ayA = anchor_coord[(b * MM + mi) * 3 + 1];
    const float azA = anchor_coord[(b * MM + mi) * 3 + 2];
    const float a2A = __fadd_rn(__fadd_rn(__fmul_rn(axA, axA), __fmul_rn(ayA, ayA)), __fmul_rn(azA, azA));
    const float axB = anchor_coord[(b * MM + mi + 1) * 3 + 0];
    const float ayB = anchor_coord[(b * MM + mi + 1) * 3 + 1];
    const float azB = anchor_coord[(b * MM + mi + 1) * 3 + 2];
    const float a2B = __fadd_rn(__fadd_rn(__fmul_rn(axB, axB), __fmul_rn(ayB, ayB)), __fmul_rn(azB, azB));
    const float axC = anchor_coord[(b * MM + mi + 2) * 3 + 0];
    const float ayC = anchor_coord[(b * MM + mi + 2) * 3 + 1];
    const float azC = anchor_coord[(b * MM + mi + 2) * 3 + 2];
    const float a2C = __fadd_rn(__fadd_rn(__fmul_rn(axC, axC), __fmul_rn(ayC, ayC)), __fmul_rn(azC, azC));
    const float axD = anchor_coord[(b * MM + mi + 3) * 3 + 0];
    const float ayD = anchor_coord[(b * MM + mi + 3) * 3 + 1];
    const float azD = anchor_coord[(b * MM + mi + 3) * 3 + 2];
    const float a2D = __fadd_rn(__fadd_rn(__fmul_rn(axD, axD), __fmul_rn(ayD, ayD)), __fmul_rn(azD, azD));

    const float4* c4b = c4buf + (size_t)b * NN;

    // distances for FOUR anchors per point load (per-key formula bit-identical)
    unsigned kregA[PJ], kregB[PJ], kregC[PJ], kregD[PJ];
    unsigned tminA = 0xFFFFFFFFu, tminB = 0xFFFFFFFFu, tminC = 0xFFFFFFFFu, tminD = 0xFFFFFFFFu;
    #pragma unroll
    for (int j = 0; j < PJ; j++) {
        const int i = tid + KT * j;
        const float4 cq = c4b[i];           // ONE load feeds four anchors
        float dtA = __fadd_rn(__fadd_rn(__fmul_rn(axA, cq.x), __fmul_rn(ayA, cq.y)), __fmul_rn(azA, cq.z));
        float d2A = __fadd_rn(__fsub_rn(a2A, __fmul_rn(2.0f, dtA)), cq.w);
        unsigned ubA = __float_as_uint(d2A);
        ubA ^= (unsigned)((int)ubA >> 31) | 0x80000000u;
        kregA[j] = ubA; tminA = tminA < ubA ? tminA : ubA;
        float dtB = __fadd_rn(__fadd_rn(__fmul_rn(axB, cq.x), __fmul_rn(ayB, cq.y)), __fmul_rn(azB, cq.z));
        float d2B = __fadd_rn(__fsub_rn(a2B, __fmul_rn(2.0f, dtB)), cq.w);
        unsigned ubB = __float_as_uint(d2B);
        ubB ^= (unsigned)((int)ubB >> 31) | 0x80000000u;
        kregB[j] = ubB; tminB = tminB < ubB ? tminB : ubB;
        float dtC = __fadd_rn(__fadd_rn(__fmul_rn(axC, cq.x), __fmul_rn(ayC, cq.y)), __fmul_rn(azC, cq.z));
        float d2C = __fadd_rn(__fsub_rn(a2C, __fmul_rn(2.0f, dtC)), cq.w);
        unsigned ubC = __float_as_uint(d2C);
        ubC ^= (unsigned)((int)ubC >> 31) | 0x80000000u;
        kregC[j] = ubC; tminC = tminC < ubC ? tminC : ubC;
        float dtD = __fadd_rn(__fadd_rn(__fmul_rn(axD, cq.x), __fmul_rn(ayD, cq.y)), __fmul_rn(azD, cq.z));
        float d2D = __fadd_rn(__fsub_rn(a2D, __fmul_rn(2.0f, dtD)), cq.w);
        unsigned ubD = __float_as_uint(d2D);
        ubD ^= (unsigned)((int)ubD >> 31) | 0x80000000u;
        kregD[j] = ubD; tminD = tminD < ubD ? tminD : ubD;
    }

    // U per anchor: max over 32 designated thread-minima (lanes 0-3 x 8 waves)
    // => >=32 keys <= U => T <= U.
    unsigned umA = tminA, umB = tminB, umC = tminC, umD = tminD;
    umA = max(umA, (unsigned)__shfl_xor((int)umA, 1)); umA = max(umA, (unsigned)__shfl_xor((int)umA, 2));
    umB = max(umB, (unsigned)__shfl_xor((int)umB, 1)); umB = max(umB, (unsigned)__shfl_xor((int)umB, 2));
    umC = max(umC, (unsigned)__shfl_xor((int)umC, 1)); umC = max(umC, (unsigned)__shfl_xor((int)umC, 2));
    umD = max(umD, (unsigned)__shfl_xor((int)umD, 1)); umD = max(umD, (unsigned)__shfl_xor((int)umD, 2));
    if (lane == 0) { wmax[0][w] = umA; wmax[1][w] = umB; wmax[2][w] = umC; wmax[3][w] = umD; }
    if (tid < KAB) nsel[tid] = 0;
    __syncthreads();
    unsigned UA = wmax[0][0], UB = wmax[1][0], UC = wmax[2][0], UD = wmax[3][0];
    #pragma unroll
    for (int q = 1; q < 8; q++) {
        UA = max(UA, wmax[0][q]); UB = max(UB, wmax[1][q]);
        UC = max(UC, wmax[2][q]); UD = max(UD, wmax[3][q]);
    }

    unsigned prefA = 0, prefB = 0, prefC = 0, prefD = 0, pmask = 0;
    unsigned kA = KNB, kB = KNB, kC = KNB, kD = KNB;
    const int hc = w >> 2;                  // waves 0-3 -> copy 0, 4-7 -> copy 1

    #pragma unroll
    for (int pass = 0; pass < 4; pass++) {
        const int sh = 24 - 8 * pass;
        unsigned* hf = &hist[0][0][0];      // 2048 entries
        #pragma unroll
        for (int q = 0; q < 4; q++) hf[tid + KT * q] = 0;
        __syncthreads();
        if (pass == 0) {
            #pragma unroll
            for (int j = 0; j < PJ; j++) {
                if (kregA[j] <= UA) atomicAdd(&hist[0][hc][kregA[j] >> 24], 1u);
                if (kregB[j] <= UB) atomicAdd(&hist[1][hc][kregB[j] >> 24], 1u);
                if (kregC[j] <= UC) atomicAdd(&hist[2][hc][kregC[j] >> 24], 1u);
                if (kregD[j] <= UD) atomicAdd(&hist[3][hc][kregD[j] >> 24], 1u);
            }
        } else {
            #pragma unroll
            for (int j = 0; j < PJ; j++) {
                if ((kregA[j] & pmask) == prefA) atomicAdd(&hist[0][hc][(kregA[j] >> sh) & 0xFFu], 1u);
                if ((kregB[j] & pmask) == prefB) atomicAdd(&hist[1][hc][(kregB[j] >> sh) & 0xFFu], 1u);
                if ((kregC[j] & pmask) == prefC) atomicAdd(&hist[2][hc][(kregC[j] >> sh) & 0xFFu], 1u);
                if ((kregD[j] & pmask) == prefD) atomicAdd(&hist[3][hc][(kregD[j] >> sh) & 0xFFu], 1u);
            }
        }
        __syncthreads();
        // parallel dual-anchor bin selection per 256-thread group
        const int aa = (tid < 256) ? 0 : 2;       // group's first anchor
        const int bin = tid & 255;
        const int wg = w & 3;                     // wave index within group
        const unsigned h0 = hist[aa][0][bin] + hist[aa][1][bin];
        const unsigned h1 = hist[aa + 1][0][bin] + hist[aa + 1][1][bin];
        unsigned v0 = h0, v1 = h1;
        #pragma unroll
        for (int d = 1; d < 64; d <<= 1) {
            unsigned t0 = __shfl_up(v0, d);
            unsigned t1 = __shfl_up(v1, d);
            if (lane >= d) { v0 += t0; v1 += t1; }
        }
        if (lane == 63) { wtot[aa][wg] = v0; wtot[aa + 1][wg] = v1; }
        __syncthreads();
        {
            unsigned off0 = 0, off1 = 0;
            #pragma unroll
            for (int ww = 0; ww < 3; ww++) if (ww < wg) { off0 += wtot[aa][ww]; off1 += wtot[aa + 1][ww]; }
            v0 += off0; v1 += off1;
            const unsigned k0 = (aa == 0) ? kA : kC;
            const unsigned k1 = (aa == 0) ? kB : kD;
            const unsigned excl0 = v0 - h0, excl1 = v1 - h1;
            if (excl0 < k0 && k0 <= v0) { bc[aa][0] = (unsigned)bin; bc[aa][1] = k0 - excl0; }
            if (excl1 < k1 && k1 <= v1) { bc[aa + 1][0] = (unsigned)bin; bc[aa + 1][1] = k1 - excl1; }
        }
        __syncthreads();
        prefA |= bc[0][0] << sh; kA = bc[0][1];
        prefB |= bc[1][0] << sh; kB = bc[1][1];
        prefC |= bc[2][0] << sh; kC = bc[2][1];
        prefD |= bc[3][0] << sh; kD = bc[3][1];
        pmask |= 0xFFu << sh;
    }
    const unsigned TA = prefA, TB = prefB, TC = prefC, TD = prefD;

    // emission: all keys < T (set order irrelevant downstream)
    unsigned tmA = 0, tmB = 0, tmC = 0, tmD = 0;
    #pragma unroll
    for (int j = 0; j < PJ; j++) {
        if (kregA[j] < TA) { unsigned p = atomicAdd(&nsel[0], 1u); sel_s[0][p] = tid + KT * j; }
        else if (kregA[j] == TA) tmA |= 1u << j;
        if (kregB[j] < TB) { unsigned p = atomicAdd(&nsel[1], 1u); sel_s[1][p] = tid + KT * j; }
        else if (kregB[j] == TB) tmB |= 1u << j;
        if (kregC[j] < TC) { unsigned p = atomicAdd(&nsel[2], 1u); sel_s[2][p] = tid + KT * j; }
        else if (kregC[j] == TC) tmC |= 1u << j;
        if (kregD[j] < TD) { unsigned p = atomicAdd(&nsel[3], 1u); sel_s[3][p] = tid + KT * j; }
        else if (kregD[j] == TD) tmD |= 1u << j;
    }
    __syncthreads();
    // ties per anchor (>=1 round each since n_lt < KNB); increasing index order
    #pragma unroll
    for (int a = 0; a < KAB; a++) {
        const unsigned tmask = (a == 0) ? tmA : (a == 1) ? tmB : (a == 2) ? tmC : tmD;
        const unsigned n_lt = nsel[a];
        const unsigned needed = KNB - n_lt;
        int last = -1;
        for (unsigned r = 0; r < needed; r++) {
            if (tid == 0) selcell[a] = 0x7fffffff;
            __syncthreads();
            unsigned m = tmask;
            while (m) {
                int j = __ffs(m) - 1; m &= m - 1;
                int idx = tid + KT * j;
                if (idx > last) atomicMin(&selcell[a], idx);
            }
            __syncthreads();
            last = selcell[a];
            if (tid == 0) sel_s[a][n_lt + r] = last;
            __syncthreads();
        }
    }

    // write indices for all anchors; per-batch max ||delta|| (norms may mix anchors:
    // all feed the same per-batch max cell — validated r20 pattern)
    if (tid < 128) {
        const int a = tid >> 5;             // 0..3
        const int s = tid & 31;
        const int j = sel_s[a][s];
        idxbuf[(size_t)(a0 + a) * KNB + s] = j;
        const float4 cq = c4b[j];
        const float ax = (a == 0) ? axA : (a == 1) ? axB : (a == 2) ? axC : axD;
        const float ay = (a == 0) ? ayA : (a == 1) ? ayB : (a == 2) ? ayC : ayD;
        const float az = (a == 0) ? azA : (a == 1) ? azB : (a == 2) ? azC : azD;
        float dx = __fsub_rn(cq.x, ax);
        float dy = __fsub_rn(cq.y, ay);
        float dz = __fsub_rn(cq.z, az);
        float nrm = sqrtf(dx * dx + dy * dy + dz * dz);
        #pragma unroll
        for (int off = 32; off; off >>= 1) nrm = fmaxf(nrm, __shfl_xor(nrm, off));
        if (lane == 0) atomicMax(&maxnorm[b], __float_as_int(nrm));
    }
}

// ---------------- fused gather + MLP + maxpool: FOUR anchors per block (validated round 13) ----------------
__global__ __launch_bounds__(256, 4) void mlp_kernel(
    const float* __restrict__ feat, const float* __restrict__ coord,
    const float* __restrict__ anchor_feat, const float* __restrict__ anchor_coord,
    const float* __restrict__ W1, const float* __restrict__ b1,
    const float* __restrict__ g1, const float* __restrict__ be1,
    const float* __restrict__ W2, const float* __restrict__ b2,
    const float* __restrict__ g2, const float* __restrict__ be2,
    const int* __restrict__ maxnorm, const int* __restrict__ idxbuf,
    float* __restrict__ out)
{
    __shared__ __align__(16) float xst[AB][CIN * XP];  // x^T per anchor; rows 0..63 reused as h1^T
    __shared__ int sel[AB][KNB];

    const int a0g = blockIdx.x * AB;      // first anchor of this block
    const int b   = a0g >> 11;            // all AB anchors share the batch
    const int tid = threadIdx.x;
    const int w = tid >> 6, lane = tid & 63;
    const int g = tid >> 5, c = tid & 31; // group (k-quad) and channel-thread

    if (tid < AB * KNB) sel[tid >> 5][tid & 31] = idxbuf[(size_t)a0g * KNB + tid];
    __syncthreads();

    const float mn = __int_as_float(maxnorm[b]);

    // ---- gather: wave w owns anchor w (coalesced: lane = feature channel) ----
    {
        const int mi = (a0g + w) & (MM - 1);
        const float af = anchor_feat[((size_t)b * MM + mi) * CC + lane];
        #pragma unroll 8
        for (int kk = 0; kk < KNB; kk++) {
            const int nj = sel[w][kk];
            xst[w][(3 + lane) * XP + kk] = feat[((size_t)b * NN + nj) * CC + lane] - af;
        }
    }
    for (int t = tid; t < AB * KNB * 3; t += 256) {
        const int a = t / 96, r = t % 96, k = r / 3, j = r % 3;
        const int mi = (a0g + a) & (MM - 1);
        const int nj = sel[a][k];
        float d = __fsub_rn(coord[((size_t)b * NN + nj) * 3 + j],
                            anchor_coord[((size_t)b * MM + mi) * 3 + j]);
        xst[a][j * XP + k] = __fdiv_rn(d, mn);
    }
    __syncthreads();

    // ---- stage 1: ch = 2c, 2c+1; k = 4g..4g+3 of each anchor ----
    const int ch1 = 2 * c;
    const float b1a = b1[ch1], b1b = b1[ch1 + 1];
    float accA[AB][4], accB[AB][4];
    #pragma unroll
    for (int a = 0; a < AB; a++)
        #pragma unroll
        for (int kk = 0; kk < 4; kk++) { accA[a][kk] = b1a; accB[a][kk] = b1b; }
    #pragma unroll 4
    for (int j = 0; j < CIN; j++) {
        const float2 wv = *(const float2*)&W1[j * H1 + ch1];
        #pragma unroll
        for (int a = 0; a < AB; a++) {
            const float4 xq = *(const float4*)&xst[a][j * XP + 4 * g];
            accA[a][0] = fmaf(xq.x, wv.x, accA[a][0]);  accB[a][0] = fmaf(xq.x, wv.y, accB[a][0]);
            accA[a][1] = fmaf(xq.y, wv.x, accA[a][1]);  accB[a][1] = fmaf(xq.y, wv.y, accB[a][1]);
            accA[a][2] = fmaf(xq.z, wv.x, accA[a][2]);  accB[a][2] = fmaf(xq.z, wv.y, accB[a][2]);
            accA[a][3] = fmaf(xq.w, wv.x, accA[a][3]);  accB[a][3] = fmaf(xq.w, wv.y, accB[a][3]);
        }
    }
    const float g1a = g1[ch1], g1b = g1[ch1 + 1];
    const float be1a = be1[ch1], be1b = be1[ch1 + 1];
    float y1A[AB][4], y1B[AB][4];
    #pragma unroll
    for (int a = 0; a < AB; a++) {
        #pragma unroll
        for (int kk = 0; kk < 4; kk++) {
            float s  = accA[a][kk] + accB[a][kk];
            float s2 = accA[a][kk] * accA[a][kk] + accB[a][kk] * accB[a][kk];
            #pragma unroll
            for (int off = 16; off; off >>= 1) { s += __shfl_xor(s, off); s2 += __shfl_xor(s2, off); }
            float mu  = s  * (1.0f / H1);
            float var = s2 * (1.0f / H1) - mu * mu;
            float r = rsqrtf(var + 1e-6f);
            y1A[a][kk] = fmaxf(fmaf((accA[a][kk] - mu) * r, g1a, be1a), 0.0f);
            y1B[a][kk] = fmaxf(fmaf((accB[a][kk] - mu) * r, g1b, be1b), 0.0f);
        }
    }
    __syncthreads();                 // all x reads complete before overlay
    #pragma unroll
    for (int a = 0; a < AB; a++)
        #pragma unroll
        for (int kk = 0; kk < 4; kk++) {
            xst[a][ch1 * XP + 4 * g + kk]       = y1A[a][kk];
            xst[a][(ch1 + 1) * XP + 4 * g + kk] = y1B[a][kk];
        }
    __syncthreads();

    // ---- stage 2: ch = 4c..4c+3; k = 4g..4g+3 of each anchor ----
    const int ch2 = 4 * c;
    const float4 b2v = *(const float4*)&b2[ch2];
    float a2c[AB][16];   // [anchor][ci*4+kk]
    #pragma unroll
    for (int a = 0; a < AB; a++)
        #pragma unroll
        for (int kk = 0; kk < 4; kk++) {
            a2c[a][0 * 4 + kk] = b2v.x; a2c[a][1 * 4 + kk] = b2v.y;
            a2c[a][2 * 4 + kk] = b2v.z; a2c[a][3 * 4 + kk] = b2v.w;
        }
    #pragma unroll 2
    for (int j = 0; j < H1; j++) {
        const float4 wv = *(const float4*)&W2[j * H2 + ch2];
        #pragma unroll
        for (int a = 0; a < AB; a++) {
            const float4 hq = *(const float4*)&xst[a][j * XP + 4 * g];
            a2c[a][0]  = fmaf(hq.x, wv.x, a2c[a][0]);  a2c[a][1]  = fmaf(hq.y, wv.x, a2c[a][1]);
            a2c[a][2]  = fmaf(hq.z, wv.x, a2c[a][2]);  a2c[a][3]  = fmaf(hq.w, wv.x, a2c[a][3]);
            a2c[a][4]  = fmaf(hq.x, wv.y, a2c[a][4]);  a2c[a][5]  = fmaf(hq.y, wv.y, a2c[a][5]);
            a2c[a][6]  = fmaf(hq.z, wv.y, a2c[a][6]);  a2c[a][7]  = fmaf(hq.w, wv.y, a2c[a][7]);
            a2c[a][8]  = fmaf(hq.x, wv.z, a2c[a][8]);  a2c[a][9]  = fmaf(hq.y, wv.z, a2c[a][9]);
            a2c[a][10] = fmaf(hq.z, wv.z, a2c[a][10]); a2c[a][11] = fmaf(hq.w, wv.z, a2c[a][11]);
            a2c[a][12] = fmaf(hq.x, wv.w, a2c[a][12]); a2c[a][13] = fmaf(hq.y, wv.w, a2c[a][13]);
            a2c[a][14] = fmaf(hq.z, wv.w, a2c[a][14]); a2c[a][15] = fmaf(hq.w, wv.w, a2c[a][15]);
        }
    }
    const float4 g2v  = *(const float4*)&g2[ch2];
    const float4 be2v = *(const float4*)&be2[ch2];
    float mx[AB][4];
    #pragma unroll
    for (int a = 0; a < AB; a++) {
        mx[a][0] = -INFINITY; mx[a][1] = -INFINITY; mx[a][2] = -INFINITY; mx[a][3] = -INFINITY;
        #pragma unroll
        for (int kk = 0; kk < 4; kk++) {
            float v0 = a2c[a][kk], v1 = a2c[a][4 + kk], v2 = a2c[a][8 + kk], v3 = a2c[a][12 + kk];
            float s  = (v0 + v1) + (v2 + v3);
            float s2 = (v0 * v0 + v1 * v1) + (v2 * v2 + v3 * v3);
            #pragma unroll
            for (int off = 16; off; off >>= 1) { s += __shfl_xor(s, off); s2 += __shfl_xor(s2, off); }
            float mu  = s  * (1.0f / H2);
            float var = s2 * (1.0f / H2) - mu * mu;
            float r = rsqrtf(var + 1e-6f);
            mx[a][0] = fmaxf(mx[a][0], fmaxf(fmaf((v0 - mu) * r, g2v.x, be2v.x), 0.0f));
            mx[a][1] = fmaxf(mx[a][1], fmaxf(fmaf((v1 - mu) * r, g2v.y, be2v.y), 0.0f));
            mx[a][2] = fmaxf(mx[a][2], fmaxf(fmaf((v2 - mu) * r, g2v.z, be2v.z), 0.0f));
            mx[a][3] = fmaxf(mx[a][3], fmaxf(fmaf((v3 - mu) * r, g2v.w, be2v.w), 0.0f));
        }
    }
    __syncthreads();                 // xst dead: alias as pmax[a][g][128]
    float* pmaxp = &xst[0][0];
    #pragma unroll
    for (int a = 0; a < AB; a++) {
        float4 q; q.x = mx[a][0]; q.y = mx[a][1]; q.z = mx[a][2]; q.w = mx[a][3];
        *(float4*)&pmaxp[(a * 8 + g) * H2 + ch2] = q;
    }
    __syncthreads();
    #pragma unroll
    for (int t = tid; t < AB * H2; t += 256) {
        const int a = t >> 7, ch = t & 127;
        float vv = pmaxp[(a * 8 + 0) * H2 + ch];
        #pragma unroll
        for (int gg = 1; gg < 8; gg++) vv = fmaxf(vv, pmaxp[(a * 8 + gg) * H2 + ch]);
        out[(size_t)(a0g + a) * H2 + ch] = vv;
    }
}

extern "C" void kernel_launch(void* const* d_in, const int* in_sizes, int n_in,
                              void* d_out, int out_size, void* d_ws, size_t ws_size,
                              hipStream_t stream) {
    const float* feat         = (const float*)d_in[0];
    const float* coord        = (const float*)d_in[1];
    const float* anchor_feat  = (const float*)d_in[2];
    const float* anchor_coord = (const float*)d_in[3];
    const float* W1  = (const float*)d_in[4];
    const float* b1  = (const float*)d_in[5];
    const float* g1  = (const float*)d_in[6];
    const float* be1 = (const float*)d_in[7];
    const float* W2  = (const float*)d_in[8];
    const float* b2  = (const float*)d_in[9];
    const float* g2  = (const float*)d_in[10];
    const float* be2 = (const float*)d_in[11];
    float* out = (float*)d_out;

    int*    maxn   = (int*)d_ws;                                  // 16 ints
    int*    idxbuf = (int*)d_ws + 16;                             // BB*MM*KNB ints
    float4* c4buf  = (float4*)((int*)d_ws + 16 + BB * MM * KNB);  // BB*NN float4 (16B aligned)

    init_kernel<<<1, 64, 0, stream>>>(maxn);
    coord4_kernel<<<(BB * NN + 255) / 256, 256, 0, stream>>>(coord, c4buf);
    knn_kernel<<<BB * MM / KAB, KT, 0, stream>>>(c4buf, anchor_coord, idxbuf, maxn);
    mlp_kernel<<<BB * MM / AB, 256, 0, stream>>>(feat, coord, anchor_feat, anchor_coord,
                                                 W1, b1, g1, be1, W2, b2, g2, be2,
                                                 maxn, idxbuf, out);
}

// Round 23
// 204.926 us; speedup vs baseline: 1.0672x; 1.0672x over previous
//
#include <hip/hip_runtime.h>
#include <math.h>

#define BB 4
#define NN 8192
#define MM 2048
#define CC 64
#define KNB 32
#define CIN 67   // 3 + CC
#define H1 64
#define H2 128
#define XP 36    // padded row stride for x^T / h1^T tile (float4-aligned)
#define AB 4     // anchors per mlp block

// ---------------- init: zero per-batch maxnorm cells ----------------
__global__ void init_kernel(int* maxnorm) {
    if (threadIdx.x < BB) maxnorm[threadIdx.x] = 0;
}

// ---------------- coord4 pack: (cx,cy,cz,c2) per point; c2 formula bit-identical ----------------
__global__ __launch_bounds__(256) void coord4_kernel(const float* __restrict__ coord,
                                                     float4* __restrict__ c4) {
    const int t = blockIdx.x * 256 + threadIdx.x;   // t in [0, BB*NN)
    if (t < BB * NN) {
        float cx = coord[t * 3 + 0], cy = coord[t * 3 + 1], cz = coord[t * 3 + 2];
        float c2 = __fadd_rn(__fadd_rn(__fmul_rn(cx, cx), __fmul_rn(cy, cy)), __fmul_rn(cz, cz));
        float4 q; q.x = cx; q.y = cy; q.z = cz; q.w = c2;
        c4[t] = q;
    }
}

// ---------------- kNN: TWO anchors per block; register radix select + U-prefilter ----------------
// Validated round 20 (best measured). Per-anchor selection math byte-identical to
// r13/r15: monotone u32 keys, 4x8-bit radix rank, <T emission + lowest-index ties.
// Point loads / addressing / barriers / hist-zeroing amortized over 2 anchors.
__global__ __launch_bounds__(256, 4) void knn_kernel(
    const float4* __restrict__ c4buf, const float* __restrict__ anchor_coord,
    int* __restrict__ idxbuf, int* __restrict__ maxnorm)
{
    __shared__ unsigned hist[2][4][256];  // [anchor][wave][bin]
    __shared__ unsigned wmax[2][4];
    __shared__ unsigned wtot[2][4];
    __shared__ unsigned bc[2][2];         // [anchor][0]=bin, [anchor][1]=rank
    __shared__ unsigned nsel[2];
    __shared__ int      selcell[2];
    __shared__ int      sel_s[2][KNB];

    const int a0 = blockIdx.x * 2;        // even: both anchors in same batch
    const int b  = a0 >> 11;              // / MM
    const int mi = a0 & (MM - 1);
    const int tid = threadIdx.x;
    const int w = tid >> 6, lane = tid & 63;

    const float axA = anchor_coord[(b * MM + mi) * 3 + 0];
    const float ayA = anchor_coord[(b * MM + mi) * 3 + 1];
    const float azA = anchor_coord[(b * MM + mi) * 3 + 2];
    const float a2A = __fadd_rn(__fadd_rn(__fmul_rn(axA, axA), __fmul_rn(ayA, ayA)), __fmul_rn(azA, azA));
    const float axB = anchor_coord[(b * MM + mi + 1) * 3 + 0];
    const float ayB = anchor_coord[(b * MM + mi + 1) * 3 + 1];
    const float azB = anchor_coord[(b * MM + mi + 1) * 3 + 2];
    const float a2B = __fadd_rn(__fadd_rn(__fmul_rn(axB, axB), __fmul_rn(ayB, ayB)), __fmul_rn(azB, azB));

    const float4* c4b = c4buf + (size_t)b * NN;

    // distances for BOTH anchors per point load (per-anchor formula bit-identical)
    unsigned kregA[32], kregB[32];
    unsigned tminA = 0xFFFFFFFFu, tminB = 0xFFFFFFFFu;
    #pragma unroll
    for (int j = 0; j < 32; j++) {
        const int i = tid + 256 * j;
        const float4 cq = c4b[i];         // ONE load feeds two anchors
        float dtA = __fadd_rn(__fadd_rn(__fmul_rn(axA, cq.x), __fmul_rn(ayA, cq.y)), __fmul_rn(azA, cq.z));
        float d2A = __fadd_rn(__fsub_rn(a2A, __fmul_rn(2.0f, dtA)), cq.w);
        unsigned ubA = __float_as_uint(d2A);
        ubA ^= (unsigned)((int)ubA >> 31) | 0x80000000u;
        kregA[j] = ubA;
        tminA = tminA < ubA ? tminA : ubA;
        float dtB = __fadd_rn(__fadd_rn(__fmul_rn(axB, cq.x), __fmul_rn(ayB, cq.y)), __fmul_rn(azB, cq.z));
        float d2B = __fadd_rn(__fsub_rn(a2B, __fmul_rn(2.0f, dtB)), cq.w);
        unsigned ubB = __float_as_uint(d2B);
        ubB ^= (unsigned)((int)ubB >> 31) | 0x80000000u;
        kregB[j] = ubB;
        tminB = tminB < ubB ? tminB : ubB;
    }

    // U per anchor (max of 32 designated per-thread minima => T <= U)
    unsigned umA = tminA, umB = tminB;
    umA = max(umA, (unsigned)__shfl_xor((int)umA, 1));
    umA = max(umA, (unsigned)__shfl_xor((int)umA, 2));
    umA = max(umA, (unsigned)__shfl_xor((int)umA, 4));
    umB = max(umB, (unsigned)__shfl_xor((int)umB, 1));
    umB = max(umB, (unsigned)__shfl_xor((int)umB, 2));
    umB = max(umB, (unsigned)__shfl_xor((int)umB, 4));
    if (lane == 0) { wmax[0][w] = umA; wmax[1][w] = umB; }
    if (tid == 0) { nsel[0] = 0; nsel[1] = 0; }
    __syncthreads();
    const unsigned UA = max(max(wmax[0][0], wmax[0][1]), max(wmax[0][2], wmax[0][3]));
    const unsigned UB = max(max(wmax[1][0], wmax[1][1]), max(wmax[1][2], wmax[1][3]));

    unsigned prefA = 0, prefB = 0, pmask = 0;
    unsigned kA = KNB, kB = KNB;

    #pragma unroll
    for (int pass = 0; pass < 4; pass++) {
        const int sh = 24 - 8 * pass;
        unsigned* hf = &hist[0][0][0];    // 2048 entries
        #pragma unroll
        for (int q = 0; q < 8; q++) hf[tid + 256 * q] = 0;
        __syncthreads();
        if (pass == 0) {
            #pragma unroll
            for (int j = 0; j < 32; j++) {
                if (kregA[j] <= UA) atomicAdd(&hist[0][w][kregA[j] >> 24], 1u);
                if (kregB[j] <= UB) atomicAdd(&hist[1][w][kregB[j] >> 24], 1u);
            }
        } else {
            #pragma unroll
            for (int j = 0; j < 32; j++) {
                // U-check redundant for pass>=1 (== r7's exact no-filter multiset)
                if ((kregA[j] & pmask) == prefA) atomicAdd(&hist[0][w][(kregA[j] >> sh) & 0xFFu], 1u);
                if ((kregB[j] & pmask) == prefB) atomicAdd(&hist[1][w][(kregB[j] >> sh) & 0xFFu], 1u);
            }
        }
        __syncthreads();
        const unsigned hA = hist[0][0][tid] + hist[0][1][tid] + hist[0][2][tid] + hist[0][3][tid];
        const unsigned hB = hist[1][0][tid] + hist[1][1][tid] + hist[1][2][tid] + hist[1][3][tid];
        unsigned vA = hA, vB = hB;
        #pragma unroll
        for (int d = 1; d < 64; d <<= 1) {
            unsigned tA = __shfl_up(vA, d);
            unsigned tB = __shfl_up(vB, d);
            if (lane >= d) { vA += tA; vB += tB; }
        }
        if (lane == 63) { wtot[0][w] = vA; wtot[1][w] = vB; }
        __syncthreads();
        unsigned offA = 0, offB = 0;
        #pragma unroll
        for (int ww = 0; ww < 3; ww++) if (ww < w) { offA += wtot[0][ww]; offB += wtot[1][ww]; }
        vA += offA; vB += offB;
        const unsigned exclA = vA - hA, exclB = vB - hB;
        if (exclA < kA && kA <= vA) { bc[0][0] = (unsigned)tid; bc[0][1] = kA - exclA; }
        if (exclB < kB && kB <= vB) { bc[1][0] = (unsigned)tid; bc[1][1] = kB - exclB; }
        __syncthreads();
        prefA |= bc[0][0] << sh; kA = bc[0][1];
        prefB |= bc[1][0] << sh; kB = bc[1][1];
        pmask |= 0xFFu << sh;
    }
    const unsigned TA = prefA, TB = prefB;

    // emission: all keys < T (set order irrelevant downstream)
    unsigned tiemaskA = 0, tiemaskB = 0;
    #pragma unroll
    for (int j = 0; j < 32; j++) {
        unsigned kkA = kregA[j];
        if (kkA < TA) { unsigned p = atomicAdd(&nsel[0], 1u); sel_s[0][p] = tid + 256 * j; }
        else if (kkA == TA) tiemaskA |= 1u << j;
        unsigned kkB = kregB[j];
        if (kkB < TB) { unsigned p = atomicAdd(&nsel[1], 1u); sel_s[1][p] = tid + 256 * j; }
        else if (kkB == TB) tiemaskB |= 1u << j;
    }
    __syncthreads();
    // ties, anchor A (>=1 round since n_lt < KNB)
    {
        const unsigned n_lt = nsel[0];
        const unsigned needed = KNB - n_lt;
        int last = -1;
        for (unsigned r = 0; r < needed; r++) {
            if (tid == 0) selcell[0] = 0x7fffffff;
            __syncthreads();
            unsigned m = tiemaskA;
            while (m) {
                int j = __ffs(m) - 1; m &= m - 1;
                int idx = tid + 256 * j;
                if (idx > last) atomicMin(&selcell[0], idx);
            }
            __syncthreads();
            last = selcell[0];
            if (tid == 0) sel_s[0][n_lt + r] = last;
            __syncthreads();
        }
    }
    // ties, anchor B
    {
        const unsigned n_lt = nsel[1];
        const unsigned needed = KNB - n_lt;
        int last = -1;
        for (unsigned r = 0; r < needed; r++) {
            if (tid == 0) selcell[1] = 0x7fffffff;
            __syncthreads();
            unsigned m = tiemaskB;
            while (m) {
                int j = __ffs(m) - 1; m &= m - 1;
                int idx = tid + 256 * j;
                if (idx > last) atomicMin(&selcell[1], idx);
            }
            __syncthreads();
            last = selcell[1];
            if (tid == 0) sel_s[1][n_lt + r] = last;
            __syncthreads();
        }
    }

    // write indices for both anchors; per-batch max ||delta|| (one combined reduce)
    float nrm = 0.0f;
    if (tid < 64) {
        const int a = tid >> 5;           // 0: anchor A, 1: anchor B
        const int s = tid & 31;
        const int j = sel_s[a][s];
        idxbuf[(size_t)(a0 + a) * KNB + s] = j;
        const float4 cq = c4b[j];
        const float ax = a ? axB : axA, ay = a ? ayB : ayA, az = a ? azB : azA;
        float dx = __fsub_rn(cq.x, ax);
        float dy = __fsub_rn(cq.y, ay);
        float dz = __fsub_rn(cq.z, az);
        nrm = sqrtf(dx * dx + dy * dy + dz * dz);
    }
    if (tid < 64) {
        #pragma unroll
        for (int off = 32; off; off >>= 1) nrm = fmaxf(nrm, __shfl_xor(nrm, off));
        if (tid == 0) atomicMax(&maxnorm[b], __float_as_int(nrm));
    }
}

// ---------------- fused gather + MLP + maxpool: FOUR anchors per block (validated round 13) ----------------
__global__ __launch_bounds__(256, 4) void mlp_kernel(
    const float* __restrict__ feat, const float* __restrict__ coord,
    const float* __restrict__ anchor_feat, const float* __restrict__ anchor_coord,
    const float* __restrict__ W1, const float* __restrict__ b1,
    const float* __restrict__ g1, const float* __restrict__ be1,
    const float* __restrict__ W2, const float* __restrict__ b2,
    const float* __restrict__ g2, const float* __restrict__ be2,
    const int* __restrict__ maxnorm, const int* __restrict__ idxbuf,
    float* __restrict__ out)
{
    __shared__ __align__(16) float xst[AB][CIN * XP];  // x^T per anchor; rows 0..63 reused as h1^T
    __shared__ int sel[AB][KNB];

    const int a0g = blockIdx.x * AB;      // first anchor of this block
    const int b   = a0g >> 11;            // all AB anchors share the batch
    const int tid = threadIdx.x;
    const int w = tid >> 6, lane = tid & 63;
    const int g = tid >> 5, c = tid & 31; // group (k-quad) and channel-thread

    if (tid < AB * KNB) sel[tid >> 5][tid & 31] = idxbuf[(size_t)a0g * KNB + tid];
    __syncthreads();

    const float mn = __int_as_float(maxnorm[b]);

    // ---- gather: wave w owns anchor w (coalesced: lane = feature channel) ----
    {
        const int mi = (a0g + w) & (MM - 1);
        const float af = anchor_feat[((size_t)b * MM + mi) * CC + lane];
        #pragma unroll 8
        for (int kk = 0; kk < KNB; kk++) {
            const int nj = sel[w][kk];
            xst[w][(3 + lane) * XP + kk] = feat[((size_t)b * NN + nj) * CC + lane] - af;
        }
    }
    for (int t = tid; t < AB * KNB * 3; t += 256) {
        const int a = t / 96, r = t % 96, k = r / 3, j = r % 3;
        const int mi = (a0g + a) & (MM - 1);
        const int nj = sel[a][k];
        float d = __fsub_rn(coord[((size_t)b * NN + nj) * 3 + j],
                            anchor_coord[((size_t)b * MM + mi) * 3 + j]);
        xst[a][j * XP + k] = __fdiv_rn(d, mn);
    }
    __syncthreads();

    // ---- stage 1: ch = 2c, 2c+1; k = 4g..4g+3 of each anchor ----
    const int ch1 = 2 * c;
    const float b1a = b1[ch1], b1b = b1[ch1 + 1];
    float accA[AB][4], accB[AB][4];
    #pragma unroll
    for (int a = 0; a < AB; a++)
        #pragma unroll
        for (int kk = 0; kk < 4; kk++) { accA[a][kk] = b1a; accB[a][kk] = b1b; }
    #pragma unroll 4
    for (int j = 0; j < CIN; j++) {
        const float2 wv = *(const float2*)&W1[j * H1 + ch1];
        #pragma unroll
        for (int a = 0; a < AB; a++) {
            const float4 xq = *(const float4*)&xst[a][j * XP + 4 * g];
            accA[a][0] = fmaf(xq.x, wv.x, accA[a][0]);  accB[a][0] = fmaf(xq.x, wv.y, accB[a][0]);
            accA[a][1] = fmaf(xq.y, wv.x, accA[a][1]);  accB[a][1] = fmaf(xq.y, wv.y, accB[a][1]);
            accA[a][2] = fmaf(xq.z, wv.x, accA[a][2]);  accB[a][2] = fmaf(xq.z, wv.y, accB[a][2]);
            accA[a][3] = fmaf(xq.w, wv.x, accA[a][3]);  accB[a][3] = fmaf(xq.w, wv.y, accB[a][3]);
        }
    }
    const float g1a = g1[ch1], g1b = g1[ch1 + 1];
    const float be1a = be1[ch1], be1b = be1[ch1 + 1];
    float y1A[AB][4], y1B[AB][4];
    #pragma unroll
    for (int a = 0; a < AB; a++) {
        #pragma unroll
        for (int kk = 0; kk < 4; kk++) {
            float s  = accA[a][kk] + accB[a][kk];
            float s2 = accA[a][kk] * accA[a][kk] + accB[a][kk] * accB[a][kk];
            #pragma unroll
            for (int off = 16; off; off >>= 1) { s += __shfl_xor(s, off); s2 += __shfl_xor(s2, off); }
            float mu  = s  * (1.0f / H1);
            float var = s2 * (1.0f / H1) - mu * mu;
            float r = rsqrtf(var + 1e-6f);
            y1A[a][kk] = fmaxf(fmaf((accA[a][kk] - mu) * r, g1a, be1a), 0.0f);
            y1B[a][kk] = fmaxf(fmaf((accB[a][kk] - mu) * r, g1b, be1b), 0.0f);
        }
    }
    __syncthreads();                 // all x reads complete before overlay
    #pragma unroll
    for (int a = 0; a < AB; a++)
        #pragma unroll
        for (int kk = 0; kk < 4; kk++) {
            xst[a][ch1 * XP + 4 * g + kk]       = y1A[a][kk];
            xst[a][(ch1 + 1) * XP + 4 * g + kk] = y1B[a][kk];
        }
    __syncthreads();

    // ---- stage 2: ch = 4c..4c+3; k = 4g..4g+3 of each anchor ----
    const int ch2 = 4 * c;
    const float4 b2v = *(const float4*)&b2[ch2];
    float a2c[AB][16];   // [anchor][ci*4+kk]
    #pragma unroll
    for (int a = 0; a < AB; a++)
        #pragma unroll
        for (int kk = 0; kk < 4; kk++) {
            a2c[a][0 * 4 + kk] = b2v.x; a2c[a][1 * 4 + kk] = b2v.y;
            a2c[a][2 * 4 + kk] = b2v.z; a2c[a][3 * 4 + kk] = b2v.w;
        }
    #pragma unroll 2
    for (int j = 0; j < H1; j++) {
        const float4 wv = *(const float4*)&W2[j * H2 + ch2];
        #pragma unroll
        for (int a = 0; a < AB; a++) {
            const float4 hq = *(const float4*)&xst[a][j * XP + 4 * g];
            a2c[a][0]  = fmaf(hq.x, wv.x, a2c[a][0]);  a2c[a][1]  = fmaf(hq.y, wv.x, a2c[a][1]);
            a2c[a][2]  = fmaf(hq.z, wv.x, a2c[a][2]);  a2c[a][3]  = fmaf(hq.w, wv.x, a2c[a][3]);
            a2c[a][4]  = fmaf(hq.x, wv.y, a2c[a][4]);  a2c[a][5]  = fmaf(hq.y, wv.y, a2c[a][5]);
            a2c[a][6]  = fmaf(hq.z, wv.y, a2c[a][6]);  a2c[a][7]  = fmaf(hq.w, wv.y, a2c[a][7]);
            a2c[a][8]  = fmaf(hq.x, wv.z, a2c[a][8]);  a2c[a][9]  = fmaf(hq.y, wv.z, a2c[a][9]);
            a2c[a][10] = fmaf(hq.z, wv.z, a2c[a][10]); a2c[a][11] = fmaf(hq.w, wv.z, a2c[a][11]);
            a2c[a][12] = fmaf(hq.x, wv.w, a2c[a][12]); a2c[a][13] = fmaf(hq.y, wv.w, a2c[a][13]);
            a2c[a][14] = fmaf(hq.z, wv.w, a2c[a][14]); a2c[a][15] = fmaf(hq.w, wv.w, a2c[a][15]);
        }
    }
    const float4 g2v  = *(const float4*)&g2[ch2];
    const float4 be2v = *(const float4*)&be2[ch2];
    float mx[AB][4];
    #pragma unroll
    for (int a = 0; a < AB; a++) {
        mx[a][0] = -INFINITY; mx[a][1] = -INFINITY; mx[a][2] = -INFINITY; mx[a][3] = -INFINITY;
        #pragma unroll
        for (int kk = 0; kk < 4; kk++) {
            float v0 = a2c[a][kk], v1 = a2c[a][4 + kk], v2 = a2c[a][8 + kk], v3 = a2c[a][12 + kk];
            float s  = (v0 + v1) + (v2 + v3);
            float s2 = (v0 * v0 + v1 * v1) + (v2 * v2 + v3 * v3);
            #pragma unroll
            for (int off = 16; off; off >>= 1) { s += __shfl_xor(s, off); s2 += __shfl_xor(s2, off); }
            float mu  = s  * (1.0f / H2);
            float var = s2 * (1.0f / H2) - mu * mu;
            float r = rsqrtf(var + 1e-6f);
            mx[a][0] = fmaxf(mx[a][0], fmaxf(fmaf((v0 - mu) * r, g2v.x, be2v.x), 0.0f));
            mx[a][1] = fmaxf(mx[a][1], fmaxf(fmaf((v1 - mu) * r, g2v.y, be2v.y), 0.0f));
            mx[a][2] = fmaxf(mx[a][2], fmaxf(fmaf((v2 - mu) * r, g2v.z, be2v.z), 0.0f));
            mx[a][3] = fmaxf(mx[a][3], fmaxf(fmaf((v3 - mu) * r, g2v.w, be2v.w), 0.0f));
        }
    }
    __syncthreads();                 // xst dead: alias as pmax[a][g][128]
    float* pmaxp = &xst[0][0];
    #pragma unroll
    for (int a = 0; a < AB; a++) {
        float4 q; q.x = mx[a][0]; q.y = mx[a][1]; q.z = mx[a][2]; q.w = mx[a][3];
        *(float4*)&pmaxp[(a * 8 + g) * H2 + ch2] = q;
    }
    __syncthreads();
    #pragma unroll
    for (int t = tid; t < AB * H2; t += 256) {
        const int a = t >> 7, ch = t & 127;
        float vv = pmaxp[(a * 8 + 0) * H2 + ch];
        #pragma unroll
        for (int gg = 1; gg < 8; gg++) vv = fmaxf(vv, pmaxp[(a * 8 + gg) * H2 + ch]);
        out[(size_t)(a0g + a) * H2 + ch] = vv;
    }
}

extern "C" void kernel_launch(void* const* d_in, const int* in_sizes, int n_in,
                              void* d_out, int out_size, void* d_ws, size_t ws_size,
                              hipStream_t stream) {
    const float* feat         = (const float*)d_in[0];
    const float* coord        = (const float*)d_in[1];
    const float* anchor_feat  = (const float*)d_in[2];
    const float* anchor_coord = (const float*)d_in[3];
    const float* W1  = (const float*)d_in[4];
    const float* b1  = (const float*)d_in[5];
    const float* g1  = (const float*)d_in[6];
    const float* be1 = (const float*)d_in[7];
    const float* W2  = (const float*)d_in[8];
    const float* b2  = (const float*)d_in[9];
    const float* g2  = (const float*)d_in[10];
    const float* be2 = (const float*)d_in[11];
    float* out = (float*)d_out;

    int*    maxn   = (int*)d_ws;                                  // 16 ints
    int*    idxbuf = (int*)d_ws + 16;                             // BB*MM*KNB ints
    float4* c4buf  = (float4*)((int*)d_ws + 16 + BB * MM * KNB);  // BB*NN float4 (16B aligned)

    init_kernel<<<1, 64, 0, stream>>>(maxn);
    coord4_kernel<<<(BB * NN + 255) / 256, 256, 0, stream>>>(coord, c4buf);
    knn_kernel<<<BB * MM / 2, 256, 0, stream>>>(c4buf, anchor_coord, idxbuf, maxn);
    mlp_kernel<<<BB * MM / AB, 256, 0, stream>>>(feat, coord, anchor_feat, anchor_coord,
                                                 W1, b1, g1, be1, W2, b2, g2, be2,
                                                 maxn, idxbuf, out);
}